// Round 9
// baseline (34.757 us; speedup 1.0000x reference)
//
#include <hip/hip_runtime.h>

#define BT 128
#define NTHREADS 512

typedef __attribute__((ext_vector_type(8))) __bf16 bf16x8;
typedef __attribute__((ext_vector_type(4))) __bf16 bf16x4;
typedef __attribute__((ext_vector_type(4))) float f32x4;

__device__ __forceinline__ __bf16 f2bf(float f) { return (__bf16)f; }
__device__ __forceinline__ f32x4 ld4(const float* p) { return *(const f32x4*)p; }

// Single fused kernel, BT=128 / 512 threads (8 waves, 16 elements/wave).
// LDS: SA (W1 [64][200] bf16 during GEMM1, reused as Hs [128][72]) +
//      WL2 [96][72] = 39.4 KB. 2 blocks/CU (thread-limited) = 16 waves/CU.
// Order: random gathers issue FIRST, L2-hot weight convert fills the shadow.
__global__ __launch_bounds__(NTHREADS, 4)
void ncf_one(const int* __restrict__ user_ids, const int* __restrict__ movie_ids,
             const int* __restrict__ genre_ids, const int* __restrict__ offsets,
             const float* __restrict__ user_mem_w, const float* __restrict__ movie_mem_w,
             const float* __restrict__ ue_gmf, const float* __restrict__ me_gmf,
             const float* __restrict__ ge_gmf,
             const float* __restrict__ ue_mlp, const float* __restrict__ me_mlp,
             const float* __restrict__ ge_mlp,
             const float* __restrict__ w1, const float* __restrict__ b1,
             const float* __restrict__ w2, const float* __restrict__ b2,
             const float* __restrict__ w_out, const float* __restrict__ b_out,
             float* __restrict__ out, int Btot, int totG)
{
    __shared__ __bf16 SA[64 * 200];    // W1 during GEMM1; Hs [128][72] afterwards
    __shared__ __bf16 WL2[96 * 72];    // row stride 144 B

    const int tid  = threadIdx.x;
    const int lane = tid & 63;
    const int wid  = tid >> 6;         // 8 waves
    const int lr   = lane & 15;
    const int lg   = lane >> 4;
    const int e0   = blockIdx.x * BT;

    // ---- per-element random gathers issue first ----
    const int erow = wid * 16 + lr;
    const int gidx = min(e0 + erow, Btot - 1);
    const int u    = user_ids[gidx];
    const int mv   = movie_ids[gidx];
    const int gs   = offsets[gidx];
    const int gend = (gidx + 1 < Btot) ? offsets[gidx + 1] : totG;
    const int cnt  = gend - gs;
    const float inv = 1.0f / (float)(cnt > 0 ? cnt : 1);

    // user/movie mlp rows (10 x 16B, independent, latency-critical)
    const float* up = ue_mlp + (size_t)u * 96 + lg * 8;
    const float* mp = me_mlp + (size_t)mv * 64 + lg * 8;
    f32x4 ua0 = ld4(up +  0), ub0 = ld4(up +  4),
          ua1 = ld4(up + 32), ub1 = ld4(up + 36),
          ua2 = ld4(up + 64), ub2 = ld4(up + 68);
    f32x4 ma0 = ld4(mp +  0), mb0 = ld4(mp +  4),
          ma1 = ld4(mp + 32), mb1 = ld4(mp + 36);

    // GMF rows (10 x 16B)
    const float* ugp = ue_gmf + (size_t)u * 96 + 4 * lg;
    f32x4 ug0 = ld4(ugp +  0), ug1 = ld4(ugp + 16), ug2 = ld4(ugp + 32),
          ug3 = ld4(ugp + 48), ug4 = ld4(ugp + 64), ug5 = ld4(ugp + 80);
    const float* mgp = me_gmf + (size_t)mv * 64 + 4 * lg;
    f32x4 mg0 = ld4(mgp + 0), mg1 = ld4(mgp + 16), mg2 = ld4(mgp + 32), mg3 = ld4(mgp + 48);
    const float um = user_mem_w[u];
    const float mm = movie_mem_w[mv];

    // genre pass (L1-resident tables)
    f32x4 gg0 = {0.f,0.f,0.f,0.f}, gg1 = {0.f,0.f,0.f,0.f};
    f32x4 gm0 = {0.f,0.f,0.f,0.f}, gm1 = {0.f,0.f,0.f,0.f};
    for (int i = gs; i < gend; ++i) {
        const int g = genre_ids[i];
        const float* pg = ge_gmf + (size_t)g * 32 + 4 * lg;
        gg0 += ld4(pg);
        gg1 += ld4(pg + 16);
        const float* pm = ge_mlp + (size_t)g * 32 + 8 * lg;
        gm0 += ld4(pm);
        gm1 += ld4(pm + 4);
    }

    // ---- weight convert into LDS (L2-hot broadcast, fills gather shadow) ----
    #pragma unroll
    for (int j = 0; j < 6; ++j) {                // w1: 3072 f32x4, rows of 48
        const int v = tid + j * 512;
        const int r = v / 48, c4 = v % 48;
        f32x4 a = ld4(w1 + (size_t)v * 4);
        bf16x4 t; t[0]=f2bf(a[0]); t[1]=f2bf(a[1]); t[2]=f2bf(a[2]); t[3]=f2bf(a[3]);
        *(bf16x4*)&SA[r * 200 + c4 * 4] = t;
    }
    #pragma unroll
    for (int j = 0; j < 3; ++j) {                // w2: 1536 f32x4, rows of 16
        const int v = tid + j * 512;
        const int r = v >> 4, c4 = v & 15;
        f32x4 a = ld4(w2 + (size_t)v * 4);
        bf16x4 t; t[0]=f2bf(a[0]); t[1]=f2bf(a[1]); t[2]=f2bf(a[2]); t[3]=f2bf(a[3]);
        *(bf16x4*)&WL2[r * 72 + c4 * 4] = t;
    }

    // ---- A-fragments ----
    bf16x8 fr[6];
    {
        bf16x8 t;
        t[0]=f2bf(ua0[0]); t[1]=f2bf(ua0[1]); t[2]=f2bf(ua0[2]); t[3]=f2bf(ua0[3]);
        t[4]=f2bf(ub0[0]); t[5]=f2bf(ub0[1]); t[6]=f2bf(ub0[2]); t[7]=f2bf(ub0[3]);
        fr[0] = t;
        t[0]=f2bf(ua1[0]); t[1]=f2bf(ua1[1]); t[2]=f2bf(ua1[2]); t[3]=f2bf(ua1[3]);
        t[4]=f2bf(ub1[0]); t[5]=f2bf(ub1[1]); t[6]=f2bf(ub1[2]); t[7]=f2bf(ub1[3]);
        fr[1] = t;
        t[0]=f2bf(ua2[0]); t[1]=f2bf(ua2[1]); t[2]=f2bf(ua2[2]); t[3]=f2bf(ua2[3]);
        t[4]=f2bf(ub2[0]); t[5]=f2bf(ub2[1]); t[6]=f2bf(ub2[2]); t[7]=f2bf(ub2[3]);
        fr[2] = t;
        t[0]=f2bf(ma0[0]); t[1]=f2bf(ma0[1]); t[2]=f2bf(ma0[2]); t[3]=f2bf(ma0[3]);
        t[4]=f2bf(mb0[0]); t[5]=f2bf(mb0[1]); t[6]=f2bf(mb0[2]); t[7]=f2bf(mb0[3]);
        fr[3] = t;
        t[0]=f2bf(ma1[0]); t[1]=f2bf(ma1[1]); t[2]=f2bf(ma1[2]); t[3]=f2bf(ma1[3]);
        t[4]=f2bf(mb1[0]); t[5]=f2bf(mb1[1]); t[6]=f2bf(mb1[2]); t[7]=f2bf(mb1[3]);
        fr[4] = t;
        t[0]=f2bf(gm0[0]*inv); t[1]=f2bf(gm0[1]*inv); t[2]=f2bf(gm0[2]*inv); t[3]=f2bf(gm0[3]*inv);
        t[4]=f2bf(gm1[0]*inv); t[5]=f2bf(gm1[1]*inv); t[6]=f2bf(gm1[2]*inv); t[7]=f2bf(gm1[3]*inv);
        fr[5] = t;
    }

    // ---- GMF dot (f32 exact) ----
    float pval;
    {
        const float* wop = w_out + 4 * lg;
        f32x4 wo0 = ld4(wop), wo1 = ld4(wop + 16), wo2 = ld4(wop + 32),
              wo3 = ld4(wop + 48), wo4 = ld4(wop + 64), wo5 = ld4(wop + 80);
        float s = 0.f;
        #pragma unroll
        for (int q = 0; q < 4; ++q) {
            s += ug0[q]*mg0[q]*wo0[q] + ug1[q]*mg1[q]*wo1[q]
               + ug2[q]*mg2[q]*wo2[q] + ug3[q]*mg3[q]*wo3[q];
            s += ug4[q]*(gg0[q]*inv)*wo4[q] + ug5[q]*(gg1[q]*inv)*wo5[q];
        }
        if (lg == 0) s += um + mm + b_out[0];
        s += __shfl_xor(s, 16);
        s += __shfl_xor(s, 32);
        pval = s;
    }

    __syncthreads();   // barrier 1: W1/W2 in LDS

    // ---- GEMM1: X[128x192] @ W1^T -> acc1 ----
    f32x4 acc1[4] = {};
    #pragma unroll
    for (int kt = 0; kt < 6; ++kt) {
        #pragma unroll
        for (int nt = 0; nt < 4; ++nt) {
            bf16x8 bw = *(const bf16x8*)&SA[(nt * 16 + lr) * 200 + kt * 32 + lg * 8];
            acc1[nt] = __builtin_amdgcn_mfma_f32_16x16x32_bf16(fr[kt], bw, acc1[nt], 0, 0, 0);
        }
    }

    __syncthreads();   // barrier 2: W1 dead -> SA reusable as Hs

    #pragma unroll
    for (int nt = 0; nt < 4; ++nt) {
        const float bv = b1[nt * 16 + lr];
        #pragma unroll
        for (int r = 0; r < 4; ++r) {
            float v = acc1[nt][r] + bv;
            v = v > 0.f ? v : 0.f;
            SA[(wid * 16 + lg * 4 + r) * 72 + nt * 16 + lr] = f2bf(v);
        }
    }
    __syncthreads();   // barrier 3: Hs visible

    // ---- GEMM2: H[128x64] @ W2^T, fused epilogue ----
    f32x4 acc2[6] = {};
    #pragma unroll
    for (int kt = 0; kt < 2; ++kt) {
        bf16x8 av = *(const bf16x8*)&SA[(wid * 16 + lr) * 72 + kt * 32 + lg * 8];
        #pragma unroll
        for (int nt = 0; nt < 6; ++nt) {
            bf16x8 bw = *(const bf16x8*)&WL2[(nt * 16 + lr) * 72 + kt * 32 + lg * 8];
            acc2[nt] = __builtin_amdgcn_mfma_f32_16x16x32_bf16(av, bw, acc2[nt], 0, 0, 0);
        }
    }

    float s0 = 0.f, s1 = 0.f, s2 = 0.f, s3 = 0.f;
    #pragma unroll
    for (int nt = 0; nt < 6; ++nt) {
        const int col = nt * 16 + lr;
        const float b2v = b2[col];
        const float wo  = w_out[96 + col];
        float v;
        v = acc2[nt][0] + b2v; v = v > 0.f ? v : 0.f; s0 += v * wo;
        v = acc2[nt][1] + b2v; v = v > 0.f ? v : 0.f; s1 += v * wo;
        v = acc2[nt][2] + b2v; v = v > 0.f ? v : 0.f; s2 += v * wo;
        v = acc2[nt][3] + b2v; v = v > 0.f ? v : 0.f; s3 += v * wo;
    }
    #pragma unroll
    for (int mask = 1; mask <= 8; mask <<= 1) {
        s0 += __shfl_xor(s0, mask);
        s1 += __shfl_xor(s1, mask);
        s2 += __shfl_xor(s2, mask);
        s3 += __shfl_xor(s3, mask);
    }
    const float p0 = __shfl(pval, lg * 4 + 0);
    const float p1 = __shfl(pval, lg * 4 + 1);
    const float p2 = __shfl(pval, lg * 4 + 2);
    const float p3 = __shfl(pval, lg * 4 + 3);

    if (lr == 0) {
        const int rowb = e0 + wid * 16 + lg * 4;
        if (rowb + 0 < Btot) out[rowb + 0] = p0 + s0;
        if (rowb + 1 < Btot) out[rowb + 1] = p1 + s1;
        if (rowb + 2 < Btot) out[rowb + 2] = p2 + s2;
        if (rowb + 3 < Btot) out[rowb + 3] = p3 + s3;
    }
}

extern "C" void kernel_launch(void* const* d_in, const int* in_sizes, int n_in,
                              void* d_out, int out_size, void* d_ws, size_t ws_size,
                              hipStream_t stream) {
    const int*   user_ids    = (const int*)d_in[0];
    const int*   movie_ids   = (const int*)d_in[1];
    const int*   genre_ids   = (const int*)d_in[2];
    const int*   offsets     = (const int*)d_in[3];
    const float* user_mem_w  = (const float*)d_in[4];
    const float* movie_mem_w = (const float*)d_in[5];
    const float* ue_gmf      = (const float*)d_in[6];
    const float* me_gmf      = (const float*)d_in[7];
    const float* ge_gmf      = (const float*)d_in[8];
    const float* ue_mlp      = (const float*)d_in[9];
    const float* me_mlp      = (const float*)d_in[10];
    const float* ge_mlp      = (const float*)d_in[11];
    const float* w1          = (const float*)d_in[12];
    const float* b1          = (const float*)d_in[13];
    const float* w2          = (const float*)d_in[14];
    const float* b2          = (const float*)d_in[15];
    const float* w_out       = (const float*)d_in[16];
    const float* b_out       = (const float*)d_in[17];

    const int Btot = in_sizes[0];
    const int totG = in_sizes[2];

    const int grid = (Btot + BT - 1) / BT;
    ncf_one<<<grid, NTHREADS, 0, stream>>>(
        user_ids, movie_ids, genre_ids, offsets,
        user_mem_w, movie_mem_w,
        ue_gmf, me_gmf, ge_gmf,
        ue_mlp, me_mlp, ge_mlp,
        w1, b1, w2, b2, w_out, b_out,
        (float*)d_out, Btot, totG);
}

// Round 10
// 28.092 us; speedup vs baseline: 1.2373x; 1.2373x over previous
//
#include <hip/hip_runtime.h>

#define BT 64
#define NTHREADS 256

typedef __attribute__((ext_vector_type(8))) __bf16 bf16x8;
typedef __attribute__((ext_vector_type(4))) __bf16 bf16x4;
typedef __attribute__((ext_vector_type(4))) float f32x4;

__device__ __forceinline__ __bf16 f2bf(float f) { return (__bf16)f; }
__device__ __forceinline__ f32x4 ld4(const float* p) { return *(const f32x4*)p; }

// Single fused kernel (round-8 configuration — best measured: 28.3 us).
// LDS: SA (W1 [64][200] bf16 during GEMM1, reused as Hs [64][72]) +
//      WL2 [96][72] = 39.4 KB -> 4 blocks/CU, 16 waves/CU.
// Order: weight-convert FIRST (registers die into LDS immediately, keeping
// peak VGPR ~90 under the 128 cap), then random gathers. R9 showed that
// reordering gathers first causes spills and a 6.5 us regression.
__global__ __launch_bounds__(NTHREADS, 4)
void ncf_one(const int* __restrict__ user_ids, const int* __restrict__ movie_ids,
             const int* __restrict__ genre_ids, const int* __restrict__ offsets,
             const float* __restrict__ user_mem_w, const float* __restrict__ movie_mem_w,
             const float* __restrict__ ue_gmf, const float* __restrict__ me_gmf,
             const float* __restrict__ ge_gmf,
             const float* __restrict__ ue_mlp, const float* __restrict__ me_mlp,
             const float* __restrict__ ge_mlp,
             const float* __restrict__ w1, const float* __restrict__ b1,
             const float* __restrict__ w2, const float* __restrict__ b2,
             const float* __restrict__ w_out, const float* __restrict__ b_out,
             float* __restrict__ out, int Btot, int totG)
{
    __shared__ __bf16 SA[64 * 200];    // WL1 during GEMM1; Hs afterwards
    __shared__ __bf16 WL2[96 * 72];    // row stride 144 B

    const int tid  = threadIdx.x;
    const int lane = tid & 63;
    const int wid  = tid >> 6;
    const int lr   = lane & 15;
    const int lg   = lane >> 4;
    const int e0   = blockIdx.x * BT;

    // ---- weight convert into LDS (L2-hot broadcast reads) ----
    #pragma unroll
    for (int j = 0; j < 12; ++j) {               // w1: 3072 f32x4, rows of 48
        const int v = tid + j * 256;
        const int r = v / 48, c4 = v % 48;
        f32x4 a = ld4(w1 + (size_t)v * 4);
        bf16x4 t; t[0]=f2bf(a[0]); t[1]=f2bf(a[1]); t[2]=f2bf(a[2]); t[3]=f2bf(a[3]);
        *(bf16x4*)&SA[r * 200 + c4 * 4] = t;
    }
    #pragma unroll
    for (int j = 0; j < 6; ++j) {                // w2: 1536 f32x4, rows of 16
        const int v = tid + j * 256;
        const int r = v >> 4, c4 = v & 15;
        f32x4 a = ld4(w2 + (size_t)v * 4);
        bf16x4 t; t[0]=f2bf(a[0]); t[1]=f2bf(a[1]); t[2]=f2bf(a[2]); t[3]=f2bf(a[3]);
        *(bf16x4*)&WL2[r * 72 + c4 * 4] = t;
    }

    // ---- per-element gather (4 lanes/element) ----
    const int erow = wid * 16 + lr;
    const int gidx = min(e0 + erow, Btot - 1);
    const int u    = user_ids[gidx];
    const int mv   = movie_ids[gidx];
    const int gs   = offsets[gidx];
    const int gend = (gidx + 1 < Btot) ? offsets[gidx + 1] : totG;
    const int cnt  = gend - gs;
    const float inv = 1.0f / (float)(cnt > 0 ? cnt : 1);

    // single genre pass: gmf chunks gg0/gg1, mlp chunks gm0/gm1
    f32x4 gg0 = {0.f,0.f,0.f,0.f}, gg1 = {0.f,0.f,0.f,0.f};
    f32x4 gm0 = {0.f,0.f,0.f,0.f}, gm1 = {0.f,0.f,0.f,0.f};
    for (int i = gs; i < gend; ++i) {
        const int g = genre_ids[i];
        const float* pg = ge_gmf + (size_t)g * 32 + 4 * lg;
        gg0 += ld4(pg);
        gg1 += ld4(pg + 16);
        const float* pm = ge_mlp + (size_t)g * 32 + 8 * lg;
        gm0 += ld4(pm);
        gm1 += ld4(pm + 4);
    }

    // A-fragments: lane (lr,lg) holds X[erow][kt*32 + lg*8 .. +7]
    bf16x8 fr[6];
    {
        const float* up = ue_mlp + (size_t)u * 96 + lg * 8;
        const float* mp = me_mlp + (size_t)mv * 64 + lg * 8;
        #pragma unroll
        for (int kt = 0; kt < 3; ++kt) {
            f32x4 a = ld4(up + kt * 32), b = ld4(up + kt * 32 + 4);
            bf16x8 t;
            t[0]=f2bf(a[0]); t[1]=f2bf(a[1]); t[2]=f2bf(a[2]); t[3]=f2bf(a[3]);
            t[4]=f2bf(b[0]); t[5]=f2bf(b[1]); t[6]=f2bf(b[2]); t[7]=f2bf(b[3]);
            fr[kt] = t;
        }
        #pragma unroll
        for (int kt = 0; kt < 2; ++kt) {
            f32x4 a = ld4(mp + kt * 32), b = ld4(mp + kt * 32 + 4);
            bf16x8 t;
            t[0]=f2bf(a[0]); t[1]=f2bf(a[1]); t[2]=f2bf(a[2]); t[3]=f2bf(a[3]);
            t[4]=f2bf(b[0]); t[5]=f2bf(b[1]); t[6]=f2bf(b[2]); t[7]=f2bf(b[3]);
            fr[3 + kt] = t;
        }
        bf16x8 t;
        t[0]=f2bf(gm0[0]*inv); t[1]=f2bf(gm0[1]*inv); t[2]=f2bf(gm0[2]*inv); t[3]=f2bf(gm0[3]*inv);
        t[4]=f2bf(gm1[0]*inv); t[5]=f2bf(gm1[1]*inv); t[6]=f2bf(gm1[2]*inv); t[7]=f2bf(gm1[3]*inv);
        fr[5] = t;
    }

    // GMF dot (f32 exact)
    float pval;
    {
        float s = 0.f;
        #pragma unroll
        for (int j = 0; j < 4; ++j) {
            const int d = 4 * lg + 16 * j;
            f32x4 ug = ld4(ue_gmf + (size_t)u * 96 + d);
            f32x4 mg = ld4(me_gmf + (size_t)mv * 64 + d);
            f32x4 wo = ld4(w_out + d);
            s += ug[0]*mg[0]*wo[0] + ug[1]*mg[1]*wo[1] + ug[2]*mg[2]*wo[2] + ug[3]*mg[3]*wo[3];
        }
        {
            const int d = 64 + 4 * lg;
            f32x4 ug = ld4(ue_gmf + (size_t)u * 96 + d);
            f32x4 wo = ld4(w_out + d);
            s += ug[0]*gg0[0]*inv*wo[0] + ug[1]*gg0[1]*inv*wo[1]
               + ug[2]*gg0[2]*inv*wo[2] + ug[3]*gg0[3]*inv*wo[3];
        }
        {
            const int d = 80 + 4 * lg;
            f32x4 ug = ld4(ue_gmf + (size_t)u * 96 + d);
            f32x4 wo = ld4(w_out + d);
            s += ug[0]*gg1[0]*inv*wo[0] + ug[1]*gg1[1]*inv*wo[1]
               + ug[2]*gg1[2]*inv*wo[2] + ug[3]*gg1[3]*inv*wo[3];
        }
        if (lg == 0) s += user_mem_w[u] + movie_mem_w[mv] + b_out[0];
        s += __shfl_xor(s, 16);
        s += __shfl_xor(s, 32);
        pval = s;
    }

    __syncthreads();   // barrier 1: WL1/WL2 ready

    // ---- GEMM1: X[64x192] @ W1^T -> acc1 ----
    f32x4 acc1[4] = {};
    #pragma unroll
    for (int kt = 0; kt < 6; ++kt) {
        #pragma unroll
        for (int nt = 0; nt < 4; ++nt) {
            bf16x8 bw = *(const bf16x8*)&SA[(nt * 16 + lr) * 200 + kt * 32 + lg * 8];
            acc1[nt] = __builtin_amdgcn_mfma_f32_16x16x32_bf16(fr[kt], bw, acc1[nt], 0, 0, 0);
        }
    }

    __syncthreads();   // barrier 2: all waves done reading WL1 -> SA reusable as Hs

    // bias + relu -> Hs (in SA)
    #pragma unroll
    for (int nt = 0; nt < 4; ++nt) {
        const float bv = b1[nt * 16 + lr];
        #pragma unroll
        for (int r = 0; r < 4; ++r) {
            float v = acc1[nt][r] + bv;
            v = v > 0.f ? v : 0.f;
            SA[(wid * 16 + lg * 4 + r) * 72 + nt * 16 + lr] = f2bf(v);
        }
    }
    __syncthreads();   // barrier 3: Hs visible

    // ---- GEMM2: H[64x64] @ W2^T -> [64x96], fused epilogue ----
    f32x4 acc2[6] = {};
    #pragma unroll
    for (int kt = 0; kt < 2; ++kt) {
        bf16x8 av = *(const bf16x8*)&SA[(wid * 16 + lr) * 72 + kt * 32 + lg * 8];
        #pragma unroll
        for (int nt = 0; nt < 6; ++nt) {
            bf16x8 bw = *(const bf16x8*)&WL2[(nt * 16 + lr) * 72 + kt * 32 + lg * 8];
            acc2[nt] = __builtin_amdgcn_mfma_f32_16x16x32_bf16(av, bw, acc2[nt], 0, 0, 0);
        }
    }

    float s0 = 0.f, s1 = 0.f, s2 = 0.f, s3 = 0.f;
    #pragma unroll
    for (int nt = 0; nt < 6; ++nt) {
        const int col = nt * 16 + lr;
        const float b2v = b2[col];
        const float wo  = w_out[96 + col];
        float v;
        v = acc2[nt][0] + b2v; v = v > 0.f ? v : 0.f; s0 += v * wo;
        v = acc2[nt][1] + b2v; v = v > 0.f ? v : 0.f; s1 += v * wo;
        v = acc2[nt][2] + b2v; v = v > 0.f ? v : 0.f; s2 += v * wo;
        v = acc2[nt][3] + b2v; v = v > 0.f ? v : 0.f; s3 += v * wo;
    }
    #pragma unroll
    for (int mask = 1; mask <= 8; mask <<= 1) {
        s0 += __shfl_xor(s0, mask);
        s1 += __shfl_xor(s1, mask);
        s2 += __shfl_xor(s2, mask);
        s3 += __shfl_xor(s3, mask);
    }
    const float p0 = __shfl(pval, lg * 4 + 0);
    const float p1 = __shfl(pval, lg * 4 + 1);
    const float p2 = __shfl(pval, lg * 4 + 2);
    const float p3 = __shfl(pval, lg * 4 + 3);

    if (lr == 0) {
        const int rowb = e0 + wid * 16 + lg * 4;
        if (rowb + 0 < Btot) out[rowb + 0] = p0 + s0;
        if (rowb + 1 < Btot) out[rowb + 1] = p1 + s1;
        if (rowb + 2 < Btot) out[rowb + 2] = p2 + s2;
        if (rowb + 3 < Btot) out[rowb + 3] = p3 + s3;
    }
}

extern "C" void kernel_launch(void* const* d_in, const int* in_sizes, int n_in,
                              void* d_out, int out_size, void* d_ws, size_t ws_size,
                              hipStream_t stream) {
    const int*   user_ids    = (const int*)d_in[0];
    const int*   movie_ids   = (const int*)d_in[1];
    const int*   genre_ids   = (const int*)d_in[2];
    const int*   offsets     = (const int*)d_in[3];
    const float* user_mem_w  = (const float*)d_in[4];
    const float* movie_mem_w = (const float*)d_in[5];
    const float* ue_gmf      = (const float*)d_in[6];
    const float* me_gmf      = (const float*)d_in[7];
    const float* ge_gmf      = (const float*)d_in[8];
    const float* ue_mlp      = (const float*)d_in[9];
    const float* me_mlp      = (const float*)d_in[10];
    const float* ge_mlp      = (const float*)d_in[11];
    const float* w1          = (const float*)d_in[12];
    const float* b1          = (const float*)d_in[13];
    const float* w2          = (const float*)d_in[14];
    const float* b2          = (const float*)d_in[15];
    const float* w_out       = (const float*)d_in[16];
    const float* b_out       = (const float*)d_in[17];

    const int Btot = in_sizes[0];
    const int totG = in_sizes[2];

    const int grid = (Btot + BT - 1) / BT;
    ncf_one<<<grid, NTHREADS, 0, stream>>>(
        user_ids, movie_ids, genre_ids, offsets,
        user_mem_w, movie_mem_w,
        ue_gmf, me_gmf, ge_gmf,
        ue_mlp, me_mlp, ge_mlp,
        w1, b1, w2, b2, w_out, b_out,
        (float*)d_out, Btot, totG);
}

// Round 11
// 27.833 us; speedup vs baseline: 1.2488x; 1.0093x over previous
//
#include <hip/hip_runtime.h>

#define BT 128
#define NTHREADS 512

typedef __attribute__((ext_vector_type(8))) __bf16 bf16x8;
typedef __attribute__((ext_vector_type(4))) __bf16 bf16x4;
typedef __attribute__((ext_vector_type(4))) float f32x4;

__device__ __forceinline__ __bf16 f2bf(float f) { return (__bf16)f; }
__device__ __forceinline__ f32x4 ld4(const float* p) { return *(const f32x4*)p; }

// R8 structure and ORDERING (weights->LDS first, registers die immediately;
// then gathers), but BT=128/512 threads: halves block count -> halves
// weight-convert L2 traffic and segment count. 2 blocks/CU x 8 waves
// = 16 waves/CU (same as R8). LDS: SA 25.6 KB (W1 [64][200]; Hs [128][72]
// = 18.4 KB after GEMM1) + WL2 13.8 KB = 39.4 KB.
__global__ __launch_bounds__(NTHREADS, 4)
void ncf_one(const int* __restrict__ user_ids, const int* __restrict__ movie_ids,
             const int* __restrict__ genre_ids, const int* __restrict__ offsets,
             const float* __restrict__ user_mem_w, const float* __restrict__ movie_mem_w,
             const float* __restrict__ ue_gmf, const float* __restrict__ me_gmf,
             const float* __restrict__ ge_gmf,
             const float* __restrict__ ue_mlp, const float* __restrict__ me_mlp,
             const float* __restrict__ ge_mlp,
             const float* __restrict__ w1, const float* __restrict__ b1,
             const float* __restrict__ w2, const float* __restrict__ b2,
             const float* __restrict__ w_out, const float* __restrict__ b_out,
             float* __restrict__ out, int Btot, int totG)
{
    __shared__ __bf16 SA[64 * 200];    // W1 during GEMM1; Hs [128][72] afterwards
    __shared__ __bf16 WL2[96 * 72];    // row stride 144 B

    const int tid  = threadIdx.x;
    const int lane = tid & 63;
    const int wid  = tid >> 6;         // 8 waves, 16 elements each
    const int lr   = lane & 15;
    const int lg   = lane >> 4;
    const int e0   = blockIdx.x * BT;

    // ---- weight convert into LDS FIRST (registers die immediately) ----
    #pragma unroll
    for (int j = 0; j < 6; ++j) {                // w1: 3072 f32x4, rows of 48
        const int v = tid + j * 512;
        const int r = v / 48, c4 = v % 48;
        f32x4 a = ld4(w1 + (size_t)v * 4);
        bf16x4 t; t[0]=f2bf(a[0]); t[1]=f2bf(a[1]); t[2]=f2bf(a[2]); t[3]=f2bf(a[3]);
        *(bf16x4*)&SA[r * 200 + c4 * 4] = t;
    }
    #pragma unroll
    for (int j = 0; j < 3; ++j) {                // w2: 1536 f32x4, rows of 16
        const int v = tid + j * 512;
        const int r = v >> 4, c4 = v & 15;
        f32x4 a = ld4(w2 + (size_t)v * 4);
        bf16x4 t; t[0]=f2bf(a[0]); t[1]=f2bf(a[1]); t[2]=f2bf(a[2]); t[3]=f2bf(a[3]);
        *(bf16x4*)&WL2[r * 72 + c4 * 4] = t;
    }

    // ---- per-element gather (4 lanes/element) ----
    const int erow = wid * 16 + lr;
    const int gidx = min(e0 + erow, Btot - 1);
    const int u    = user_ids[gidx];
    const int mv   = movie_ids[gidx];
    const int gs   = offsets[gidx];
    const int gend = (gidx + 1 < Btot) ? offsets[gidx + 1] : totG;
    const int cnt  = gend - gs;
    const float inv = 1.0f / (float)(cnt > 0 ? cnt : 1);

    // single genre pass: gmf chunks gg0/gg1, mlp chunks gm0/gm1
    f32x4 gg0 = {0.f,0.f,0.f,0.f}, gg1 = {0.f,0.f,0.f,0.f};
    f32x4 gm0 = {0.f,0.f,0.f,0.f}, gm1 = {0.f,0.f,0.f,0.f};
    for (int i = gs; i < gend; ++i) {
        const int g = genre_ids[i];
        const float* pg = ge_gmf + (size_t)g * 32 + 4 * lg;
        gg0 += ld4(pg);
        gg1 += ld4(pg + 16);
        const float* pm = ge_mlp + (size_t)g * 32 + 8 * lg;
        gm0 += ld4(pm);
        gm1 += ld4(pm + 4);
    }

    // A-fragments: lane (lr,lg) holds X[erow][kt*32 + lg*8 .. +7]
    bf16x8 fr[6];
    {
        const float* up = ue_mlp + (size_t)u * 96 + lg * 8;
        const float* mp = me_mlp + (size_t)mv * 64 + lg * 8;
        #pragma unroll
        for (int kt = 0; kt < 3; ++kt) {
            f32x4 a = ld4(up + kt * 32), b = ld4(up + kt * 32 + 4);
            bf16x8 t;
            t[0]=f2bf(a[0]); t[1]=f2bf(a[1]); t[2]=f2bf(a[2]); t[3]=f2bf(a[3]);
            t[4]=f2bf(b[0]); t[5]=f2bf(b[1]); t[6]=f2bf(b[2]); t[7]=f2bf(b[3]);
            fr[kt] = t;
        }
        #pragma unroll
        for (int kt = 0; kt < 2; ++kt) {
            f32x4 a = ld4(mp + kt * 32), b = ld4(mp + kt * 32 + 4);
            bf16x8 t;
            t[0]=f2bf(a[0]); t[1]=f2bf(a[1]); t[2]=f2bf(a[2]); t[3]=f2bf(a[3]);
            t[4]=f2bf(b[0]); t[5]=f2bf(b[1]); t[6]=f2bf(b[2]); t[7]=f2bf(b[3]);
            fr[3 + kt] = t;
        }
        bf16x8 t;
        t[0]=f2bf(gm0[0]*inv); t[1]=f2bf(gm0[1]*inv); t[2]=f2bf(gm0[2]*inv); t[3]=f2bf(gm0[3]*inv);
        t[4]=f2bf(gm1[0]*inv); t[5]=f2bf(gm1[1]*inv); t[6]=f2bf(gm1[2]*inv); t[7]=f2bf(gm1[3]*inv);
        fr[5] = t;
    }

    // GMF dot (f32 exact)
    float pval;
    {
        float s = 0.f;
        #pragma unroll
        for (int j = 0; j < 4; ++j) {
            const int d = 4 * lg + 16 * j;
            f32x4 ug = ld4(ue_gmf + (size_t)u * 96 + d);
            f32x4 mg = ld4(me_gmf + (size_t)mv * 64 + d);
            f32x4 wo = ld4(w_out + d);
            s += ug[0]*mg[0]*wo[0] + ug[1]*mg[1]*wo[1] + ug[2]*mg[2]*wo[2] + ug[3]*mg[3]*wo[3];
        }
        {
            const int d = 64 + 4 * lg;
            f32x4 ug = ld4(ue_gmf + (size_t)u * 96 + d);
            f32x4 wo = ld4(w_out + d);
            s += ug[0]*gg0[0]*inv*wo[0] + ug[1]*gg0[1]*inv*wo[1]
               + ug[2]*gg0[2]*inv*wo[2] + ug[3]*gg0[3]*inv*wo[3];
        }
        {
            const int d = 80 + 4 * lg;
            f32x4 ug = ld4(ue_gmf + (size_t)u * 96 + d);
            f32x4 wo = ld4(w_out + d);
            s += ug[0]*gg1[0]*inv*wo[0] + ug[1]*gg1[1]*inv*wo[1]
               + ug[2]*gg1[2]*inv*wo[2] + ug[3]*gg1[3]*inv*wo[3];
        }
        if (lg == 0) s += user_mem_w[u] + movie_mem_w[mv] + b_out[0];
        s += __shfl_xor(s, 16);
        s += __shfl_xor(s, 32);
        pval = s;
    }

    __syncthreads();   // barrier 1: W1/W2 in LDS

    // ---- GEMM1: X[128x192] @ W1^T -> acc1 ----
    f32x4 acc1[4] = {};
    #pragma unroll
    for (int kt = 0; kt < 6; ++kt) {
        #pragma unroll
        for (int nt = 0; nt < 4; ++nt) {
            bf16x8 bw = *(const bf16x8*)&SA[(nt * 16 + lr) * 200 + kt * 32 + lg * 8];
            acc1[nt] = __builtin_amdgcn_mfma_f32_16x16x32_bf16(fr[kt], bw, acc1[nt], 0, 0, 0);
        }
    }

    __syncthreads();   // barrier 2: W1 dead -> SA reusable as Hs

    // bias + relu -> Hs (in SA)
    #pragma unroll
    for (int nt = 0; nt < 4; ++nt) {
        const float bv = b1[nt * 16 + lr];
        #pragma unroll
        for (int r = 0; r < 4; ++r) {
            float v = acc1[nt][r] + bv;
            v = v > 0.f ? v : 0.f;
            SA[(wid * 16 + lg * 4 + r) * 72 + nt * 16 + lr] = f2bf(v);
        }
    }
    __syncthreads();   // barrier 3: Hs visible

    // ---- GEMM2: H[128x64] @ W2^T -> [128x96], fused epilogue ----
    f32x4 acc2[6] = {};
    #pragma unroll
    for (int kt = 0; kt < 2; ++kt) {
        bf16x8 av = *(const bf16x8*)&SA[(wid * 16 + lr) * 72 + kt * 32 + lg * 8];
        #pragma unroll
        for (int nt = 0; nt < 6; ++nt) {
            bf16x8 bw = *(const bf16x8*)&WL2[(nt * 16 + lr) * 72 + kt * 32 + lg * 8];
            acc2[nt] = __builtin_amdgcn_mfma_f32_16x16x32_bf16(av, bw, acc2[nt], 0, 0, 0);
        }
    }

    float s0 = 0.f, s1 = 0.f, s2 = 0.f, s3 = 0.f;
    #pragma unroll
    for (int nt = 0; nt < 6; ++nt) {
        const int col = nt * 16 + lr;
        const float b2v = b2[col];
        const float wo  = w_out[96 + col];
        float v;
        v = acc2[nt][0] + b2v; v = v > 0.f ? v : 0.f; s0 += v * wo;
        v = acc2[nt][1] + b2v; v = v > 0.f ? v : 0.f; s1 += v * wo;
        v = acc2[nt][2] + b2v; v = v > 0.f ? v : 0.f; s2 += v * wo;
        v = acc2[nt][3] + b2v; v = v > 0.f ? v : 0.f; s3 += v * wo;
    }
    #pragma unroll
    for (int mask = 1; mask <= 8; mask <<= 1) {
        s0 += __shfl_xor(s0, mask);
        s1 += __shfl_xor(s1, mask);
        s2 += __shfl_xor(s2, mask);
        s3 += __shfl_xor(s3, mask);
    }
    const float p0 = __shfl(pval, lg * 4 + 0);
    const float p1 = __shfl(pval, lg * 4 + 1);
    const float p2 = __shfl(pval, lg * 4 + 2);
    const float p3 = __shfl(pval, lg * 4 + 3);

    if (lr == 0) {
        const int rowb = e0 + wid * 16 + lg * 4;
        if (rowb + 0 < Btot) out[rowb + 0] = p0 + s0;
        if (rowb + 1 < Btot) out[rowb + 1] = p1 + s1;
        if (rowb + 2 < Btot) out[rowb + 2] = p2 + s2;
        if (rowb + 3 < Btot) out[rowb + 3] = p3 + s3;
    }
}

extern "C" void kernel_launch(void* const* d_in, const int* in_sizes, int n_in,
                              void* d_out, int out_size, void* d_ws, size_t ws_size,
                              hipStream_t stream) {
    const int*   user_ids    = (const int*)d_in[0];
    const int*   movie_ids   = (const int*)d_in[1];
    const int*   genre_ids   = (const int*)d_in[2];
    const int*   offsets     = (const int*)d_in[3];
    const float* user_mem_w  = (const float*)d_in[4];
    const float* movie_mem_w = (const float*)d_in[5];
    const float* ue_gmf      = (const float*)d_in[6];
    const float* me_gmf      = (const float*)d_in[7];
    const float* ge_gmf      = (const float*)d_in[8];
    const float* ue_mlp      = (const float*)d_in[9];
    const float* me_mlp      = (const float*)d_in[10];
    const float* ge_mlp      = (const float*)d_in[11];
    const float* w1          = (const float*)d_in[12];
    const float* b1          = (const float*)d_in[13];
    const float* w2          = (const float*)d_in[14];
    const float* b2          = (const float*)d_in[15];
    const float* w_out       = (const float*)d_in[16];
    const float* b_out       = (const float*)d_in[17];

    const int Btot = in_sizes[0];
    const int totG = in_sizes[2];

    const int grid = (Btot + BT - 1) / BT;
    ncf_one<<<grid, NTHREADS, 0, stream>>>(
        user_ids, movie_ids, genre_ids, offsets,
        user_mem_w, movie_mem_w,
        ue_gmf, me_gmf, ge_gmf,
        ue_mlp, me_mlp, ge_mlp,
        w1, b1, w2, b2, w_out, b_out,
        (float*)d_out, Btot, totG);
}